// Round 4
// baseline (3095.520 us; speedup 1.0000x reference)
//
#include <hip/hip_runtime.h>

// MPALayer (HAN-style): P=3 metapath GATs + semantic attention.
// Inputs/out are FLOAT32; edges int32. Path-SERIAL processing to fit the
// workspace budget (round 3's 367 MB f32 layout exceeded ws_size; 213 MB
// is proven safe from rounds 1-2). Only z persists across paths (f32);
// h is per-path scratch stored bf16 (el/er computed from f32 accs first).

#define N_NODES 50000
#define N_EDGES 400000
#define N_PATHS 3
#define DIN     128
#define NH      8
#define NO      32
#define NC      256   // NH*NO
#define HID     128

__device__ __forceinline__ float bf2f(unsigned short u) {
    return __uint_as_float(((unsigned int)u) << 16);
}
__device__ __forceinline__ unsigned short f2bf(float f) {
    unsigned int u = __float_as_uint(f);
    unsigned int r = u + 0x7FFFu + ((u >> 16) & 1u);   // RNE
    return (unsigned short)(r >> 16);
}

// ------------------------------------------------- node GEMM h = feat @ W_p
// grid ceil(N/64), block 256. Thread = (node-pair, head); 32 ch each.
__global__ __launch_bounds__(256) void gemm_node(
    const float* __restrict__ feat, const float* __restrict__ Ws,
    const float* __restrict__ al, const float* __restrict__ ar,
    unsigned short* __restrict__ hbuf, float* __restrict__ el,
    float* __restrict__ er, int p) {
    int tile = blockIdx.x * 64;
    int t = threadIdx.x;
    __shared__ float sfeat[64 * 132];   // pad 128->132

    for (int j = 0; j < 8; ++j) {
        int idx = (j * 256 + t) * 4;    // 0..8191 step 4
        int row = idx >> 7, col = idx & 127;
        int n = tile + row;
        float4 v = make_float4(0.f, 0.f, 0.f, 0.f);
        if (n < N_NODES) v = *(const float4*)(feat + (size_t)n * DIN + col);
        float* s = &sfeat[row * 132 + col];
        s[0] = v.x; s[1] = v.y; s[2] = v.z; s[3] = v.w;
    }
    __syncthreads();

    int hd = t & 7;
    int g  = t >> 3;                    // 0..31 -> node pair
    int r0 = g * 2, r1 = r0 + 1;
    const float* wbase = Ws + (size_t)p * DIN * NC + hd * 32;

    float acc0[32], acc1[32];
#pragma unroll
    for (int o = 0; o < 32; ++o) { acc0[o] = 0.f; acc1[o] = 0.f; }

#pragma unroll 2
    for (int k = 0; k < DIN; ++k) {
        float a0 = sfeat[r0 * 132 + k];
        float a1 = sfeat[r1 * 132 + k];
        const float4* w4 = (const float4*)(wbase + (size_t)k * NC);
#pragma unroll
        for (int q = 0; q < 8; ++q) {
            float4 w = w4[q];
            acc0[q*4+0] += a0 * w.x; acc0[q*4+1] += a0 * w.y;
            acc0[q*4+2] += a0 * w.z; acc0[q*4+3] += a0 * w.w;
            acc1[q*4+0] += a1 * w.x; acc1[q*4+1] += a1 * w.y;
            acc1[q*4+2] += a1 * w.z; acc1[q*4+3] += a1 * w.w;
        }
    }

    const float* alp = al + (p * NH + hd) * NO;
    const float* arp = ar + (p * NH + hd) * NO;
    float el0 = 0.f, er0 = 0.f, el1 = 0.f, er1 = 0.f;
#pragma unroll
    for (int o = 0; o < 32; ++o) {
        float a = alp[o], r = arp[o];
        el0 += acc0[o] * a; er0 += acc0[o] * r;
        el1 += acc1[o] * a; er1 += acc1[o] * r;
    }
    int n0 = tile + r0, n1 = tile + r1;
    if (n0 < N_NODES) {
        unsigned short* hb = hbuf + (size_t)n0 * NC + hd * 32;
#pragma unroll
        for (int o = 0; o < 32; ++o) hb[o] = f2bf(acc0[o]);
        el[(size_t)n0 * NH + hd] = el0;
        er[(size_t)n0 * NH + hd] = er0;
    }
    if (n1 < N_NODES) {
        unsigned short* hb = hbuf + (size_t)n1 * NC + hd * 32;
#pragma unroll
        for (int o = 0; o < 32; ++o) hb[o] = f2bf(acc1[o]);
        el[(size_t)n1 * NH + hd] = el1;
        er[(size_t)n1 * NH + hd] = er1;
    }
}

// ------------------------------------------------------------- degree count
__global__ void count_deg(const int* __restrict__ edges_p, int* __restrict__ deg) {
    int e = blockIdx.x * 256 + threadIdx.x;
    if (e >= N_EDGES) return;
    int dst = edges_p[N_EDGES + e];
    atomicAdd(&deg[dst], 1);
}

// ------------------------------------------------------- 3-phase exclusive scan
__global__ void scan_chunk(const int* __restrict__ deg, int* __restrict__ offs,
                           int* __restrict__ ctot) {
    int i = blockIdx.x * 256 + threadIdx.x;
    __shared__ int s[256];
    int v = (i < N_NODES) ? deg[i] : 0;
    int orig = v;
    for (int off = 1; off < 256; off <<= 1) {
        s[threadIdx.x] = v; __syncthreads();
        int add = (threadIdx.x >= off) ? s[threadIdx.x - off] : 0;
        __syncthreads();
        v += add;
    }
    if (i < N_NODES) offs[i] = v - orig;
    if (threadIdx.x == 255) ctot[blockIdx.x] = v;
}

__global__ void scan_tot(const int* __restrict__ ctot, int* __restrict__ cbase, int nch) {
    int t = threadIdx.x;
    __shared__ int s[256];
    int v = (t < nch) ? ctot[t] : 0;
    int orig = v;
    for (int off = 1; off < 256; off <<= 1) {
        s[t] = v; __syncthreads();
        int add = (t >= off) ? s[t - off] : 0;
        __syncthreads();
        v += add;
    }
    cbase[t] = v - orig;
}

__global__ void add_base(int* __restrict__ offs, const int* __restrict__ cbase) {
    int i = blockIdx.x * 256 + threadIdx.x;
    if (i < N_NODES) offs[i] += cbase[blockIdx.x];
}

// ------------------------------------------------------------------ CSR fill
__global__ void fill_csr(const int* __restrict__ edges_p, const int* __restrict__ offs,
                         int* __restrict__ cursor, int* __restrict__ csr) {
    int e = blockIdx.x * 256 + threadIdx.x;
    if (e >= N_EDGES) return;
    int src = edges_p[e], dst = edges_p[N_EDGES + e];
    int pos = atomicAdd(&cursor[dst], 1);
    csr[offs[dst] + pos] = src;
}

// ------------------------- Phase A: per (dst,head) segment max + exp numerators
__global__ __launch_bounds__(256) void phase_a(
    const int* __restrict__ csr, const int* __restrict__ offs, const int* __restrict__ deg,
    const float* __restrict__ el, const float* __restrict__ er,
    float* __restrict__ num, float* __restrict__ rs) {
    int t = threadIdx.x;
    int dst = blockIdx.x * 32 + (t >> 3);
    int hd = t & 7;
    if (dst >= N_NODES) return;
    int off = offs[dst];
    int d   = deg[dst];
    float erv = er[(size_t)dst * NH + hd];
    const int* cp = csr + off;
    float m = -1e30f;
    for (int j = 0; j < d; ++j) {
        int src = cp[j];
        float x = el[src * NH + hd] + erv;
        x = (x >= 0.f) ? x : 0.2f * x;
        m = fmaxf(m, x);
    }
    float s = 0.f;
    float* np_ = num + (size_t)off * NH + hd;
    for (int j = 0; j < d; ++j) {
        int src = cp[j];
        float x = el[src * NH + hd] + erv;
        x = (x >= 0.f) ? x : 0.2f * x;
        float v = expf(x - m);
        np_[(size_t)j * NH] = v;
        s += v;
    }
    rs[(size_t)dst * NH + hd] = (d > 0) ? 1.0f / s : 0.f;
}

// -------------------- Phase B: block per dst, thread per channel; z = elu(..)
__global__ __launch_bounds__(256) void phase_b(
    const int* __restrict__ csr, const int* __restrict__ offs, const int* __restrict__ deg,
    const float* __restrict__ num, const float* __restrict__ rs,
    const unsigned short* __restrict__ hbuf, const float* __restrict__ bias,
    float* __restrict__ zbuf, int p) {
    int dst = blockIdx.x;
    int c = threadIdx.x;
    int hd = c >> 5;
    int off = offs[dst];
    int d   = deg[dst];
    float rsv = rs[(size_t)dst * NH + hd];
    const int*   cp  = csr + off;
    const float* np_ = num + (size_t)off * NH;
    float acc = 0.f;
    for (int j = 0; j < d; ++j) {
        int src = cp[j];
        float a = np_[(size_t)j * NH + hd] * rsv;
        acc += a * bf2f(hbuf[(size_t)src * NC + c]);
    }
    float zv = acc + bias[p * NC + c];
    zv = (zv > 0.f) ? zv : expm1f(zv);
    zbuf[((size_t)p * N_NODES + dst) * NC + c] = zv;
}

// ----------------- semantic attention partial sums: wave per (node, path)
__global__ __launch_bounds__(256) void semantic(
    const float* __restrict__ zbuf, const float* __restrict__ W1,
    const float* __restrict__ b1, const float* __restrict__ w2,
    float* __restrict__ wpart) {
    int p = blockIdx.y;
    int w = threadIdx.x >> 6;
    int lane = threadIdx.x & 63;
    int node = blockIdx.x * 4 + w;
    __shared__ float zrow[4][260];
    __shared__ float wsum[4];

    if (node < N_NODES) {
        const float* zp = zbuf + ((size_t)p * N_NODES + node) * NC;
        float4 q = *(const float4*)(zp + lane * 4);
        zrow[w][lane * 4 + 0] = q.x;
        zrow[w][lane * 4 + 1] = q.y;
        zrow[w][lane * 4 + 2] = q.z;
        zrow[w][lane * 4 + 3] = q.w;
    }
    __syncthreads();

    float contrib = 0.f;
    if (node < N_NODES) {
        int j0 = lane * 2;                 // hidden units j0, j0+1
        float acc0 = 0.f, acc1 = 0.f;
#pragma unroll 4
        for (int k = 0; k < NC; ++k) {
            float zk = zrow[w][k];
            const float* wp = W1 + (size_t)k * HID + j0;
            acc0 += zk * wp[0];
            acc1 += zk * wp[1];
        }
        float y0 = tanhf(acc0 + b1[j0]);
        float y1 = tanhf(acc1 + b1[j0 + 1]);
        contrib = y0 * w2[j0] + y1 * w2[j0 + 1];
    }
    for (int off = 32; off > 0; off >>= 1)
        contrib += __shfl_down(contrib, off, 64);
    if (lane == 0) wsum[w] = contrib;
    __syncthreads();
    if (threadIdx.x == 0) {
        float tot = wsum[0] + wsum[1] + wsum[2] + wsum[3];
        atomicAdd(&wpart[p * 256 + (blockIdx.x & 255)], tot);
    }
}

// ------------------------------------------------------------- beta (softmax)
__global__ void compute_beta(const float* __restrict__ wpart, float* __restrict__ beta) {
    __shared__ float s[256];
    int t = threadIdx.x;
    float m[N_PATHS];
    for (int p = 0; p < N_PATHS; ++p) {
        s[t] = wpart[p * 256 + t];
        __syncthreads();
        for (int off = 128; off > 0; off >>= 1) {
            if (t < off) s[t] += s[t + off];
            __syncthreads();
        }
        m[p] = s[0] / (float)N_NODES;
        __syncthreads();
    }
    if (t == 0) {
        float mx = fmaxf(m[0], fmaxf(m[1], m[2]));
        float e0 = expf(m[0] - mx), e1 = expf(m[1] - mx), e2 = expf(m[2] - mx);
        float inv = 1.f / (e0 + e1 + e2);
        beta[0] = e0 * inv; beta[1] = e1 * inv; beta[2] = e2 * inv;
    }
}

// ----------------------------------------------------------------- final mix
__global__ __launch_bounds__(256) void final_mix(
    const float* __restrict__ zbuf, const float* __restrict__ beta,
    float* __restrict__ out) {
    int n = blockIdx.x;
    int c = threadIdx.x;
    float b0 = beta[0], b1 = beta[1], b2 = beta[2];
    size_t stride = (size_t)N_NODES * NC;
    size_t idx = (size_t)n * NC + c;
    out[idx] = b0 * zbuf[idx] + b1 * zbuf[idx + stride]
             + b2 * zbuf[idx + 2 * stride];
}

extern "C" void kernel_launch(void* const* d_in, const int* in_sizes, int n_in,
                              void* d_out, int out_size, void* d_ws, size_t ws_size,
                              hipStream_t stream) {
    const float* feat  = (const float*)d_in[0];
    const int*   edges = (const int*)d_in[1];
    const float* Ws    = (const float*)d_in[2];
    const float* al    = (const float*)d_in[3];
    const float* ar    = (const float*)d_in[4];
    const float* bias  = (const float*)d_in[5];
    const float* W1    = (const float*)d_in[6];
    const float* b1    = (const float*)d_in[7];
    const float* w2    = (const float*)d_in[8];
    float* out = (float*)d_out;

    // ---- workspace layout (256B-aligned slabs), ~199 MB total
    size_t off = 0;
    auto alloc = [&](size_t bytes) { size_t o = off; off += (bytes + 255) & ~(size_t)255; return o; };
    size_t zbuf_o  = alloc((size_t)N_PATHS * N_NODES * NC * 4);  // 153.6 MB (all paths)
    size_t hbuf_o  = alloc((size_t)N_NODES * NC * 2);            // 25.6 MB (per path, bf16)
    size_t num_o   = alloc((size_t)N_EDGES * NH * 4);            // 12.8 MB (per path)
    size_t el_o    = alloc((size_t)N_NODES * NH * 4);
    size_t er_o    = alloc((size_t)N_NODES * NH * 4);
    size_t rs_o    = alloc((size_t)N_NODES * NH * 4);
    size_t csr_o   = alloc((size_t)N_EDGES * 4);
    size_t offs_o  = alloc((size_t)N_NODES * 4);
    size_t ctot_o  = alloc(256 * 4);
    size_t cbase_o = alloc(256 * 4);
    size_t beta_o  = alloc(256);
    // zeroed-per-path region (contiguous): deg, cursor
    size_t deg_o    = alloc((size_t)N_NODES * 4);
    size_t cursor_o = alloc((size_t)N_NODES * 4);
    size_t zend_o   = off;
    size_t wpart_o  = alloc((size_t)N_PATHS * 256 * 4);
    size_t total = off;
    if (ws_size < total) return;  // fail loudly (zero output)

    char* ws = (char*)d_ws;
    float*          zbuf  = (float*)(ws + zbuf_o);
    unsigned short* hbuf  = (unsigned short*)(ws + hbuf_o);
    float* num   = (float*)(ws + num_o);
    float* el    = (float*)(ws + el_o);
    float* er    = (float*)(ws + er_o);
    float* rs    = (float*)(ws + rs_o);
    int*   csr   = (int*)(ws + csr_o);
    int*   offs  = (int*)(ws + offs_o);
    int*   ctot  = (int*)(ws + ctot_o);
    int*   cbase = (int*)(ws + cbase_o);
    float* beta  = (float*)(ws + beta_o);
    int*   deg   = (int*)(ws + deg_o);
    int*   cursor= (int*)(ws + cursor_o);
    float* wpart = (float*)(ws + wpart_o);

    const int NCH = (N_NODES + 255) / 256;   // 196 scan chunks

    hipMemsetAsync(ws + wpart_o, 0, (size_t)N_PATHS * 256 * 4, stream);

    for (int p = 0; p < N_PATHS; ++p) {
        const int* edges_p = edges + (size_t)p * 2 * N_EDGES;
        hipMemsetAsync(ws + deg_o, 0, zend_o - deg_o, stream);  // deg + cursor
        gemm_node<<<(N_NODES + 63) / 64, 256, 0, stream>>>(
            feat, Ws, al, ar, hbuf, el, er, p);
        count_deg<<<(N_EDGES + 255) / 256, 256, 0, stream>>>(edges_p, deg);
        scan_chunk<<<NCH, 256, 0, stream>>>(deg, offs, ctot);
        scan_tot<<<1, 256, 0, stream>>>(ctot, cbase, NCH);
        add_base<<<NCH, 256, 0, stream>>>(offs, cbase);
        fill_csr<<<(N_EDGES + 255) / 256, 256, 0, stream>>>(edges_p, offs, cursor, csr);
        phase_a<<<(N_NODES + 31) / 32, 256, 0, stream>>>(csr, offs, deg, el, er, num, rs);
        phase_b<<<N_NODES, 256, 0, stream>>>(csr, offs, deg, num, rs, hbuf, bias, zbuf, p);
    }
    semantic<<<dim3((N_NODES + 3) / 4, N_PATHS), 256, 0, stream>>>(
        zbuf, W1, b1, w2, wpart);
    compute_beta<<<1, 256, 0, stream>>>(wpart, beta);
    final_mix<<<N_NODES, 256, 0, stream>>>(zbuf, beta, out);
}

// Round 5
// 2207.952 us; speedup vs baseline: 1.4020x; 1.4020x over previous
//
#include <hip/hip_runtime.h>

// MPALayer (HAN-style): P=3 metapath GATs + semantic attention.
// Inputs/out FLOAT32; edges int32. Path-serial to fit ws (~199 MB).
// R4->R5: semantic rewritten as LDS-tiled GEMM (was 1128 us re-streaming
// W1 from L2 per node-row; VALU floor is ~95 us for the 9.8 GFLOP).

#define N_NODES 50000
#define N_EDGES 400000
#define N_PATHS 3
#define DIN     128
#define NH      8
#define NO      32
#define NC      256   // NH*NO
#define HID     128

__device__ __forceinline__ float bf2f(unsigned short u) {
    return __uint_as_float(((unsigned int)u) << 16);
}
__device__ __forceinline__ unsigned short f2bf(float f) {
    unsigned int u = __float_as_uint(f);
    unsigned int r = u + 0x7FFFu + ((u >> 16) & 1u);   // RNE
    return (unsigned short)(r >> 16);
}

// ------------------------------------------------- node GEMM h = feat @ W_p
__global__ __launch_bounds__(256) void gemm_node(
    const float* __restrict__ feat, const float* __restrict__ Ws,
    const float* __restrict__ al, const float* __restrict__ ar,
    unsigned short* __restrict__ hbuf, float* __restrict__ el,
    float* __restrict__ er, int p) {
    int tile = blockIdx.x * 64;
    int t = threadIdx.x;
    __shared__ float sfeat[64 * 132];   // pad 128->132

    for (int j = 0; j < 8; ++j) {
        int idx = (j * 256 + t) * 4;    // 0..8191 step 4
        int row = idx >> 7, col = idx & 127;
        int n = tile + row;
        float4 v = make_float4(0.f, 0.f, 0.f, 0.f);
        if (n < N_NODES) v = *(const float4*)(feat + (size_t)n * DIN + col);
        float* s = &sfeat[row * 132 + col];
        s[0] = v.x; s[1] = v.y; s[2] = v.z; s[3] = v.w;
    }
    __syncthreads();

    int hd = t & 7;
    int g  = t >> 3;                    // 0..31 -> node pair
    int r0 = g * 2, r1 = r0 + 1;
    const float* wbase = Ws + (size_t)p * DIN * NC + hd * 32;

    float acc0[32], acc1[32];
#pragma unroll
    for (int o = 0; o < 32; ++o) { acc0[o] = 0.f; acc1[o] = 0.f; }

#pragma unroll 2
    for (int k = 0; k < DIN; ++k) {
        float a0 = sfeat[r0 * 132 + k];
        float a1 = sfeat[r1 * 132 + k];
        const float4* w4 = (const float4*)(wbase + (size_t)k * NC);
#pragma unroll
        for (int q = 0; q < 8; ++q) {
            float4 w = w4[q];
            acc0[q*4+0] += a0 * w.x; acc0[q*4+1] += a0 * w.y;
            acc0[q*4+2] += a0 * w.z; acc0[q*4+3] += a0 * w.w;
            acc1[q*4+0] += a1 * w.x; acc1[q*4+1] += a1 * w.y;
            acc1[q*4+2] += a1 * w.z; acc1[q*4+3] += a1 * w.w;
        }
    }

    const float* alp = al + (p * NH + hd) * NO;
    const float* arp = ar + (p * NH + hd) * NO;
    float el0 = 0.f, er0 = 0.f, el1 = 0.f, er1 = 0.f;
#pragma unroll
    for (int o = 0; o < 32; ++o) {
        float a = alp[o], r = arp[o];
        el0 += acc0[o] * a; er0 += acc0[o] * r;
        el1 += acc1[o] * a; er1 += acc1[o] * r;
    }
    int n0 = tile + r0, n1 = tile + r1;
    if (n0 < N_NODES) {
        unsigned short* hb = hbuf + (size_t)n0 * NC + hd * 32;
#pragma unroll
        for (int o = 0; o < 32; ++o) hb[o] = f2bf(acc0[o]);
        el[(size_t)n0 * NH + hd] = el0;
        er[(size_t)n0 * NH + hd] = er0;
    }
    if (n1 < N_NODES) {
        unsigned short* hb = hbuf + (size_t)n1 * NC + hd * 32;
#pragma unroll
        for (int o = 0; o < 32; ++o) hb[o] = f2bf(acc1[o]);
        el[(size_t)n1 * NH + hd] = el1;
        er[(size_t)n1 * NH + hd] = er1;
    }
}

// ------------------------------------------------------------- degree count
__global__ void count_deg(const int* __restrict__ edges_p, int* __restrict__ deg) {
    int e = blockIdx.x * 256 + threadIdx.x;
    if (e >= N_EDGES) return;
    int dst = edges_p[N_EDGES + e];
    atomicAdd(&deg[dst], 1);
}

// ------------------------------------------------------- 3-phase exclusive scan
__global__ void scan_chunk(const int* __restrict__ deg, int* __restrict__ offs,
                           int* __restrict__ ctot) {
    int i = blockIdx.x * 256 + threadIdx.x;
    __shared__ int s[256];
    int v = (i < N_NODES) ? deg[i] : 0;
    int orig = v;
    for (int off = 1; off < 256; off <<= 1) {
        s[threadIdx.x] = v; __syncthreads();
        int add = (threadIdx.x >= off) ? s[threadIdx.x - off] : 0;
        __syncthreads();
        v += add;
    }
    if (i < N_NODES) offs[i] = v - orig;
    if (threadIdx.x == 255) ctot[blockIdx.x] = v;
}

__global__ void scan_tot(const int* __restrict__ ctot, int* __restrict__ cbase, int nch) {
    int t = threadIdx.x;
    __shared__ int s[256];
    int v = (t < nch) ? ctot[t] : 0;
    int orig = v;
    for (int off = 1; off < 256; off <<= 1) {
        s[t] = v; __syncthreads();
        int add = (t >= off) ? s[t - off] : 0;
        __syncthreads();
        v += add;
    }
    cbase[t] = v - orig;
}

__global__ void add_base(int* __restrict__ offs, const int* __restrict__ cbase) {
    int i = blockIdx.x * 256 + threadIdx.x;
    if (i < N_NODES) offs[i] += cbase[blockIdx.x];
}

// ------------------------------------------------------------------ CSR fill
__global__ void fill_csr(const int* __restrict__ edges_p, const int* __restrict__ offs,
                         int* __restrict__ cursor, int* __restrict__ csr) {
    int e = blockIdx.x * 256 + threadIdx.x;
    if (e >= N_EDGES) return;
    int src = edges_p[e], dst = edges_p[N_EDGES + e];
    int pos = atomicAdd(&cursor[dst], 1);
    csr[offs[dst] + pos] = src;
}

// ------------------------- Phase A: per (dst,head) segment max + exp numerators
__global__ __launch_bounds__(256) void phase_a(
    const int* __restrict__ csr, const int* __restrict__ offs, const int* __restrict__ deg,
    const float* __restrict__ el, const float* __restrict__ er,
    float* __restrict__ num, float* __restrict__ rs) {
    int t = threadIdx.x;
    int dst = blockIdx.x * 32 + (t >> 3);
    int hd = t & 7;
    if (dst >= N_NODES) return;
    int off = offs[dst];
    int d   = deg[dst];
    float erv = er[(size_t)dst * NH + hd];
    const int* cp = csr + off;
    float m = -1e30f;
    for (int j = 0; j < d; ++j) {
        int src = cp[j];
        float x = el[src * NH + hd] + erv;
        x = (x >= 0.f) ? x : 0.2f * x;
        m = fmaxf(m, x);
    }
    float s = 0.f;
    float* np_ = num + (size_t)off * NH + hd;
    for (int j = 0; j < d; ++j) {
        int src = cp[j];
        float x = el[src * NH + hd] + erv;
        x = (x >= 0.f) ? x : 0.2f * x;
        float v = expf(x - m);
        np_[(size_t)j * NH] = v;
        s += v;
    }
    rs[(size_t)dst * NH + hd] = (d > 0) ? 1.0f / s : 0.f;
}

// -------------------- Phase B: block per dst, thread per channel; z = elu(..)
__global__ __launch_bounds__(256) void phase_b(
    const int* __restrict__ csr, const int* __restrict__ offs, const int* __restrict__ deg,
    const float* __restrict__ num, const float* __restrict__ rs,
    const unsigned short* __restrict__ hbuf, const float* __restrict__ bias,
    float* __restrict__ zbuf, int p) {
    int dst = blockIdx.x;
    int c = threadIdx.x;
    int hd = c >> 5;
    int off = offs[dst];
    int d   = deg[dst];
    float rsv = rs[(size_t)dst * NH + hd];
    const int*   cp  = csr + off;
    const float* np_ = num + (size_t)off * NH;
    float acc = 0.f;
    for (int j = 0; j < d; ++j) {
        int src = cp[j];
        float a = np_[(size_t)j * NH + hd] * rsv;
        acc += a * bf2f(hbuf[(size_t)src * NC + c]);
    }
    float zv = acc + bias[p * NC + c];
    zv = (zv > 0.f) ? zv : expm1f(zv);
    zbuf[((size_t)p * N_NODES + dst) * NC + c] = zv;
}

// -------------- semantic: LDS-tiled GEMM, 64 nodes/block, K-chunks of 64.
// Thread = (node pair, 16-j group). Only the node-mean of w is needed, so
// each block emits ONE partial via atomicAdd.
__global__ __launch_bounds__(256) void semantic(
    const float* __restrict__ zbuf, const float* __restrict__ W1,
    const float* __restrict__ b1, const float* __restrict__ w2,
    float* __restrict__ wpart) {
    int p = blockIdx.y;
    int n0 = blockIdx.x * 64;
    int t = threadIdx.x;
    int pair = t >> 3;          // 0..31 -> local nodes pair*2, pair*2+1
    int j0   = (t & 7) * 16;    // 16 hidden units per thread

    __shared__ float zs[64][68];        // 17.0 KiB (pad 64->68)
    __shared__ float w1s[64 * 128];     // 32 KiB
    __shared__ float red[64][8];        // 2 KiB

    float acc0[16], acc1[16];
#pragma unroll
    for (int i = 0; i < 16; ++i) { acc0[i] = 0.f; acc1[i] = 0.f; }

    int ln0 = pair * 2, ln1 = ln0 + 1;

    for (int k0 = 0; k0 < NC; k0 += 64) {
        // stage W1 rows k0..k0+63 (contiguous 8192 floats)
        const float4* wsrc = (const float4*)(W1 + (size_t)k0 * HID);
        float4* wdst = (float4*)w1s;
#pragma unroll
        for (int i = 0; i < 8; ++i)
            wdst[i * 256 + t] = wsrc[i * 256 + t];
        // stage z[n0..n0+63][k0..k0+63]
#pragma unroll
        for (int i = 0; i < 4; ++i) {
            int q = i * 256 + t;        // 0..1023 float4 slots
            int node = q >> 4;
            int kq = (q & 15) * 4;
            int n = n0 + node;
            float4 v = make_float4(0.f, 0.f, 0.f, 0.f);
            if (n < N_NODES)
                v = *(const float4*)(zbuf + ((size_t)p * N_NODES + n) * NC + k0 + kq);
            zs[node][kq + 0] = v.x; zs[node][kq + 1] = v.y;
            zs[node][kq + 2] = v.z; zs[node][kq + 3] = v.w;
        }
        __syncthreads();

        for (int kk = 0; kk < 64; ++kk) {
            float z0 = zs[ln0][kk];
            float z1 = zs[ln1][kk];
            const float4* wr = (const float4*)(w1s + kk * 128 + j0);
#pragma unroll
            for (int i = 0; i < 4; ++i) {
                float4 w = wr[i];
                acc0[i*4+0] += z0 * w.x; acc0[i*4+1] += z0 * w.y;
                acc0[i*4+2] += z0 * w.z; acc0[i*4+3] += z0 * w.w;
                acc1[i*4+0] += z1 * w.x; acc1[i*4+1] += z1 * w.y;
                acc1[i*4+2] += z1 * w.z; acc1[i*4+3] += z1 * w.w;
            }
        }
        __syncthreads();
    }

    // epilogue: tanh + w2 dot for this thread's 16 j, 2 nodes
    float s0 = 0.f, s1 = 0.f;
#pragma unroll
    for (int i = 0; i < 16; ++i) {
        float b = b1[j0 + i], wv = w2[j0 + i];
        s0 += tanhf(acc0[i] + b) * wv;
        s1 += tanhf(acc1[i] + b) * wv;
    }
    red[ln0][t & 7] = s0;
    red[ln1][t & 7] = s1;
    __syncthreads();
    if (t < 64) {
        float s = 0.f;
#pragma unroll
        for (int g = 0; g < 8; ++g) s += red[t][g];
        if (n0 + t >= N_NODES) s = 0.f;     // mask tail nodes
        for (int o = 32; o > 0; o >>= 1)
            s += __shfl_down(s, o, 64);
        if (t == 0) atomicAdd(&wpart[p * 256 + (blockIdx.x & 255)], s);
    }
}

// ------------------------------------------------------------- beta (softmax)
__global__ void compute_beta(const float* __restrict__ wpart, float* __restrict__ beta) {
    __shared__ float s[256];
    int t = threadIdx.x;
    float m[N_PATHS];
    for (int p = 0; p < N_PATHS; ++p) {
        s[t] = wpart[p * 256 + t];
        __syncthreads();
        for (int off = 128; off > 0; off >>= 1) {
            if (t < off) s[t] += s[t + off];
            __syncthreads();
        }
        m[p] = s[0] / (float)N_NODES;
        __syncthreads();
    }
    if (t == 0) {
        float mx = fmaxf(m[0], fmaxf(m[1], m[2]));
        float e0 = expf(m[0] - mx), e1 = expf(m[1] - mx), e2 = expf(m[2] - mx);
        float inv = 1.f / (e0 + e1 + e2);
        beta[0] = e0 * inv; beta[1] = e1 * inv; beta[2] = e2 * inv;
    }
}

// ----------------------------------------------------------------- final mix
__global__ __launch_bounds__(256) void final_mix(
    const float* __restrict__ zbuf, const float* __restrict__ beta,
    float* __restrict__ out) {
    int n = blockIdx.x;
    int c = threadIdx.x;
    float b0 = beta[0], b1 = beta[1], b2 = beta[2];
    size_t stride = (size_t)N_NODES * NC;
    size_t idx = (size_t)n * NC + c;
    out[idx] = b0 * zbuf[idx] + b1 * zbuf[idx + stride]
             + b2 * zbuf[idx + 2 * stride];
}

extern "C" void kernel_launch(void* const* d_in, const int* in_sizes, int n_in,
                              void* d_out, int out_size, void* d_ws, size_t ws_size,
                              hipStream_t stream) {
    const float* feat  = (const float*)d_in[0];
    const int*   edges = (const int*)d_in[1];
    const float* Ws    = (const float*)d_in[2];
    const float* al    = (const float*)d_in[3];
    const float* ar    = (const float*)d_in[4];
    const float* bias  = (const float*)d_in[5];
    const float* W1    = (const float*)d_in[6];
    const float* b1    = (const float*)d_in[7];
    const float* w2    = (const float*)d_in[8];
    float* out = (float*)d_out;

    // ---- workspace layout (256B-aligned slabs), ~199 MB total
    size_t off = 0;
    auto alloc = [&](size_t bytes) { size_t o = off; off += (bytes + 255) & ~(size_t)255; return o; };
    size_t zbuf_o  = alloc((size_t)N_PATHS * N_NODES * NC * 4);  // 153.6 MB
    size_t hbuf_o  = alloc((size_t)N_NODES * NC * 2);            // 25.6 MB (per path, bf16)
    size_t num_o   = alloc((size_t)N_EDGES * NH * 4);            // 12.8 MB (per path)
    size_t el_o    = alloc((size_t)N_NODES * NH * 4);
    size_t er_o    = alloc((size_t)N_NODES * NH * 4);
    size_t rs_o    = alloc((size_t)N_NODES * NH * 4);
    size_t csr_o   = alloc((size_t)N_EDGES * 4);
    size_t offs_o  = alloc((size_t)N_NODES * 4);
    size_t ctot_o  = alloc(256 * 4);
    size_t cbase_o = alloc(256 * 4);
    size_t beta_o  = alloc(256);
    size_t deg_o    = alloc((size_t)N_NODES * 4);
    size_t cursor_o = alloc((size_t)N_NODES * 4);
    size_t zend_o   = off;
    size_t wpart_o  = alloc((size_t)N_PATHS * 256 * 4);
    size_t total = off;
    if (ws_size < total) return;  // fail loudly (zero output)

    char* ws = (char*)d_ws;
    float*          zbuf  = (float*)(ws + zbuf_o);
    unsigned short* hbuf  = (unsigned short*)(ws + hbuf_o);
    float* num   = (float*)(ws + num_o);
    float* el    = (float*)(ws + el_o);
    float* er    = (float*)(ws + er_o);
    float* rs    = (float*)(ws + rs_o);
    int*   csr   = (int*)(ws + csr_o);
    int*   offs  = (int*)(ws + offs_o);
    int*   ctot  = (int*)(ws + ctot_o);
    int*   cbase = (int*)(ws + cbase_o);
    float* beta  = (float*)(ws + beta_o);
    int*   deg   = (int*)(ws + deg_o);
    int*   cursor= (int*)(ws + cursor_o);
    float* wpart = (float*)(ws + wpart_o);

    const int NCH = (N_NODES + 255) / 256;   // 196 scan chunks

    hipMemsetAsync(ws + wpart_o, 0, (size_t)N_PATHS * 256 * 4, stream);

    for (int p = 0; p < N_PATHS; ++p) {
        const int* edges_p = edges + (size_t)p * 2 * N_EDGES;
        hipMemsetAsync(ws + deg_o, 0, zend_o - deg_o, stream);  // deg + cursor
        gemm_node<<<(N_NODES + 63) / 64, 256, 0, stream>>>(
            feat, Ws, al, ar, hbuf, el, er, p);
        count_deg<<<(N_EDGES + 255) / 256, 256, 0, stream>>>(edges_p, deg);
        scan_chunk<<<NCH, 256, 0, stream>>>(deg, offs, ctot);
        scan_tot<<<1, 256, 0, stream>>>(ctot, cbase, NCH);
        add_base<<<NCH, 256, 0, stream>>>(offs, cbase);
        fill_csr<<<(N_EDGES + 255) / 256, 256, 0, stream>>>(edges_p, offs, cursor, csr);
        phase_a<<<(N_NODES + 31) / 32, 256, 0, stream>>>(csr, offs, deg, el, er, num, rs);
        phase_b<<<N_NODES, 256, 0, stream>>>(csr, offs, deg, num, rs, hbuf, bias, zbuf, p);
    }
    semantic<<<dim3((N_NODES + 63) / 64, N_PATHS), 256, 0, stream>>>(
        zbuf, W1, b1, w2, wpart);
    compute_beta<<<1, 256, 0, stream>>>(wpart, beta);
    final_mix<<<N_NODES, 256, 0, stream>>>(zbuf, beta, out);
}

// Round 6
// 1206.457 us; speedup vs baseline: 2.5658x; 1.8301x over previous
//
#include <hip/hip_runtime.h>

// MPALayer (HAN-style): P=3 metapath GATs + semantic attention.
// Inputs/out FLOAT32; edges int32. Path-serial to fit ws (~199 MB).
// R5->R6: gemm_node restructured as LDS-tiled GEMM (was 474 us/path with
// VALUBusy 5% -- every k re-read W from L2 with ~3 blocks/CU to hide it).

#define N_NODES 50000
#define N_EDGES 400000
#define N_PATHS 3
#define DIN     128
#define NH      8
#define NO      32
#define NC      256   // NH*NO
#define HID     128

__device__ __forceinline__ float bf2f(unsigned short u) {
    return __uint_as_float(((unsigned int)u) << 16);
}
__device__ __forceinline__ unsigned short f2bf(float f) {
    unsigned int u = __float_as_uint(f);
    unsigned int r = u + 0x7FFFu + ((u >> 16) & 1u);   // RNE
    return (unsigned short)(r >> 16);
}

// ------------------------------------------------- node GEMM h = feat @ W_p
// grid ceil(N/64), block 256. Thread = (node-pair g, head hd): 2 nodes x 32 ch.
// K staged in LDS chunks of 32: W chunk 32x256 (32 KiB) + feat chunk 64x32
// (9 KiB padded). Inner loop is pure LDS->FMA.
__global__ __launch_bounds__(256) void gemm_node(
    const float* __restrict__ feat, const float* __restrict__ Ws,
    const float* __restrict__ al, const float* __restrict__ ar,
    unsigned short* __restrict__ hbuf, float* __restrict__ el,
    float* __restrict__ er, int p) {
    int tile = blockIdx.x * 64;
    int t = threadIdx.x;
    int hd = t & 7;
    int g  = t >> 3;                    // 0..31 -> node pair
    int ln0 = g * 2, ln1 = ln0 + 1;

    __shared__ float fs[64][36];        // 64 nodes x 32 k (pad 32->36)
    __shared__ float wls[32 * 256];     // 32 KiB

    float acc0[32], acc1[32];
#pragma unroll
    for (int o = 0; o < 32; ++o) { acc0[o] = 0.f; acc1[o] = 0.f; }

    const float* wsrc_base = Ws + (size_t)p * DIN * NC;

    for (int k0 = 0; k0 < DIN; k0 += 32) {
        // stage W rows k0..k0+31 (contiguous 8192 floats)
        const float4* wsrc = (const float4*)(wsrc_base + (size_t)k0 * NC);
        float4* wdst = (float4*)wls;
#pragma unroll
        for (int i = 0; i < 8; ++i)
            wdst[i * 256 + t] = wsrc[i * 256 + t];
        // stage feat[tile..tile+63][k0..k0+31]
#pragma unroll
        for (int i = 0; i < 2; ++i) {
            int q = i * 256 + t;        // 0..511 float4 slots
            int node = q >> 3;
            int kq = (q & 7) * 4;
            int n = tile + node;
            float4 v = make_float4(0.f, 0.f, 0.f, 0.f);
            if (n < N_NODES)
                v = *(const float4*)(feat + (size_t)n * DIN + k0 + kq);
            fs[node][kq + 0] = v.x; fs[node][kq + 1] = v.y;
            fs[node][kq + 2] = v.z; fs[node][kq + 3] = v.w;
        }
        __syncthreads();

        for (int kk = 0; kk < 32; ++kk) {
            float a0 = fs[ln0][kk];
            float a1 = fs[ln1][kk];
            const float4* wr = (const float4*)(wls + kk * 256 + hd * 32);
#pragma unroll
            for (int q = 0; q < 8; ++q) {
                float4 w = wr[q];
                acc0[q*4+0] += a0 * w.x; acc0[q*4+1] += a0 * w.y;
                acc0[q*4+2] += a0 * w.z; acc0[q*4+3] += a0 * w.w;
                acc1[q*4+0] += a1 * w.x; acc1[q*4+1] += a1 * w.y;
                acc1[q*4+2] += a1 * w.z; acc1[q*4+3] += a1 * w.w;
            }
        }
        __syncthreads();
    }

    const float* alp = al + (p * NH + hd) * NO;
    const float* arp = ar + (p * NH + hd) * NO;
    float el0 = 0.f, er0 = 0.f, el1 = 0.f, er1 = 0.f;
#pragma unroll
    for (int o = 0; o < 32; ++o) {
        float a = alp[o], r = arp[o];
        el0 += acc0[o] * a; er0 += acc0[o] * r;
        el1 += acc1[o] * a; er1 += acc1[o] * r;
    }
    int n0 = tile + ln0, n1 = tile + ln1;
    if (n0 < N_NODES) {
        unsigned short* hb = hbuf + (size_t)n0 * NC + hd * 32;
#pragma unroll
        for (int o = 0; o < 32; ++o) hb[o] = f2bf(acc0[o]);
        el[(size_t)n0 * NH + hd] = el0;
        er[(size_t)n0 * NH + hd] = er0;
    }
    if (n1 < N_NODES) {
        unsigned short* hb = hbuf + (size_t)n1 * NC + hd * 32;
#pragma unroll
        for (int o = 0; o < 32; ++o) hb[o] = f2bf(acc1[o]);
        el[(size_t)n1 * NH + hd] = el1;
        er[(size_t)n1 * NH + hd] = er1;
    }
}

// ------------------------------------------------------------- degree count
__global__ void count_deg(const int* __restrict__ edges_p, int* __restrict__ deg) {
    int e = blockIdx.x * 256 + threadIdx.x;
    if (e >= N_EDGES) return;
    int dst = edges_p[N_EDGES + e];
    atomicAdd(&deg[dst], 1);
}

// ------------------------------------------------------- 3-phase exclusive scan
__global__ void scan_chunk(const int* __restrict__ deg, int* __restrict__ offs,
                           int* __restrict__ ctot) {
    int i = blockIdx.x * 256 + threadIdx.x;
    __shared__ int s[256];
    int v = (i < N_NODES) ? deg[i] : 0;
    int orig = v;
    for (int off = 1; off < 256; off <<= 1) {
        s[threadIdx.x] = v; __syncthreads();
        int add = (threadIdx.x >= off) ? s[threadIdx.x - off] : 0;
        __syncthreads();
        v += add;
    }
    if (i < N_NODES) offs[i] = v - orig;
    if (threadIdx.x == 255) ctot[blockIdx.x] = v;
}

__global__ void scan_tot(const int* __restrict__ ctot, int* __restrict__ cbase, int nch) {
    int t = threadIdx.x;
    __shared__ int s[256];
    int v = (t < nch) ? ctot[t] : 0;
    int orig = v;
    for (int off = 1; off < 256; off <<= 1) {
        s[t] = v; __syncthreads();
        int add = (t >= off) ? s[t - off] : 0;
        __syncthreads();
        v += add;
    }
    cbase[t] = v - orig;
}

__global__ void add_base(int* __restrict__ offs, const int* __restrict__ cbase) {
    int i = blockIdx.x * 256 + threadIdx.x;
    if (i < N_NODES) offs[i] += cbase[blockIdx.x];
}

// ------------------------------------------------------------------ CSR fill
__global__ void fill_csr(const int* __restrict__ edges_p, const int* __restrict__ offs,
                         int* __restrict__ cursor, int* __restrict__ csr) {
    int e = blockIdx.x * 256 + threadIdx.x;
    if (e >= N_EDGES) return;
    int src = edges_p[e], dst = edges_p[N_EDGES + e];
    int pos = atomicAdd(&cursor[dst], 1);
    csr[offs[dst] + pos] = src;
}

// ------------------------- Phase A: per (dst,head) segment max + exp numerators
__global__ __launch_bounds__(256) void phase_a(
    const int* __restrict__ csr, const int* __restrict__ offs, const int* __restrict__ deg,
    const float* __restrict__ el, const float* __restrict__ er,
    float* __restrict__ num, float* __restrict__ rs) {
    int t = threadIdx.x;
    int dst = blockIdx.x * 32 + (t >> 3);
    int hd = t & 7;
    if (dst >= N_NODES) return;
    int off = offs[dst];
    int d   = deg[dst];
    float erv = er[(size_t)dst * NH + hd];
    const int* cp = csr + off;
    float m = -1e30f;
    for (int j = 0; j < d; ++j) {
        int src = cp[j];
        float x = el[src * NH + hd] + erv;
        x = (x >= 0.f) ? x : 0.2f * x;
        m = fmaxf(m, x);
    }
    float s = 0.f;
    float* np_ = num + (size_t)off * NH + hd;
    for (int j = 0; j < d; ++j) {
        int src = cp[j];
        float x = el[src * NH + hd] + erv;
        x = (x >= 0.f) ? x : 0.2f * x;
        float v = expf(x - m);
        np_[(size_t)j * NH] = v;
        s += v;
    }
    rs[(size_t)dst * NH + hd] = (d > 0) ? 1.0f / s : 0.f;
}

// -------------------- Phase B: block per dst, thread per channel; z = elu(..)
__global__ __launch_bounds__(256) void phase_b(
    const int* __restrict__ csr, const int* __restrict__ offs, const int* __restrict__ deg,
    const float* __restrict__ num, const float* __restrict__ rs,
    const unsigned short* __restrict__ hbuf, const float* __restrict__ bias,
    float* __restrict__ zbuf, int p) {
    int dst = blockIdx.x;
    int c = threadIdx.x;
    int hd = c >> 5;
    int off = offs[dst];
    int d   = deg[dst];
    float rsv = rs[(size_t)dst * NH + hd];
    const int*   cp  = csr + off;
    const float* np_ = num + (size_t)off * NH;
    float acc = 0.f;
    for (int j = 0; j < d; ++j) {
        int src = cp[j];
        float a = np_[(size_t)j * NH + hd] * rsv;
        acc += a * bf2f(hbuf[(size_t)src * NC + c]);
    }
    float zv = acc + bias[p * NC + c];
    zv = (zv > 0.f) ? zv : expm1f(zv);
    zbuf[((size_t)p * N_NODES + dst) * NC + c] = zv;
}

// -------------- semantic: LDS-tiled GEMM, 64 nodes/block, K-chunks of 64.
__global__ __launch_bounds__(256) void semantic(
    const float* __restrict__ zbuf, const float* __restrict__ W1,
    const float* __restrict__ b1, const float* __restrict__ w2,
    float* __restrict__ wpart) {
    int p = blockIdx.y;
    int n0 = blockIdx.x * 64;
    int t = threadIdx.x;
    int pair = t >> 3;          // 0..31 -> local nodes pair*2, pair*2+1
    int j0   = (t & 7) * 16;    // 16 hidden units per thread

    __shared__ float zs[64][68];        // 17.0 KiB (pad 64->68)
    __shared__ float w1s[64 * 128];     // 32 KiB
    __shared__ float red[64][8];        // 2 KiB

    float acc0[16], acc1[16];
#pragma unroll
    for (int i = 0; i < 16; ++i) { acc0[i] = 0.f; acc1[i] = 0.f; }

    int ln0 = pair * 2, ln1 = ln0 + 1;

    for (int k0 = 0; k0 < NC; k0 += 64) {
        const float4* wsrc = (const float4*)(W1 + (size_t)k0 * HID);
        float4* wdst = (float4*)w1s;
#pragma unroll
        for (int i = 0; i < 8; ++i)
            wdst[i * 256 + t] = wsrc[i * 256 + t];
#pragma unroll
        for (int i = 0; i < 4; ++i) {
            int q = i * 256 + t;        // 0..1023 float4 slots
            int node = q >> 4;
            int kq = (q & 15) * 4;
            int n = n0 + node;
            float4 v = make_float4(0.f, 0.f, 0.f, 0.f);
            if (n < N_NODES)
                v = *(const float4*)(zbuf + ((size_t)p * N_NODES + n) * NC + k0 + kq);
            zs[node][kq + 0] = v.x; zs[node][kq + 1] = v.y;
            zs[node][kq + 2] = v.z; zs[node][kq + 3] = v.w;
        }
        __syncthreads();

        for (int kk = 0; kk < 64; ++kk) {
            float z0 = zs[ln0][kk];
            float z1 = zs[ln1][kk];
            const float4* wr = (const float4*)(w1s + kk * 128 + j0);
#pragma unroll
            for (int i = 0; i < 4; ++i) {
                float4 w = wr[i];
                acc0[i*4+0] += z0 * w.x; acc0[i*4+1] += z0 * w.y;
                acc0[i*4+2] += z0 * w.z; acc0[i*4+3] += z0 * w.w;
                acc1[i*4+0] += z1 * w.x; acc1[i*4+1] += z1 * w.y;
                acc1[i*4+2] += z1 * w.z; acc1[i*4+3] += z1 * w.w;
            }
        }
        __syncthreads();
    }

    float s0 = 0.f, s1 = 0.f;
#pragma unroll
    for (int i = 0; i < 16; ++i) {
        float b = b1[j0 + i], wv = w2[j0 + i];
        s0 += tanhf(acc0[i] + b) * wv;
        s1 += tanhf(acc1[i] + b) * wv;
    }
    red[ln0][t & 7] = s0;
    red[ln1][t & 7] = s1;
    __syncthreads();
    if (t < 64) {
        float s = 0.f;
#pragma unroll
        for (int g = 0; g < 8; ++g) s += red[t][g];
        if (n0 + t >= N_NODES) s = 0.f;     // mask tail nodes
        for (int o = 32; o > 0; o >>= 1)
            s += __shfl_down(s, o, 64);
        if (t == 0) atomicAdd(&wpart[p * 256 + (blockIdx.x & 255)], s);
    }
}

// ------------------------------------------------------------- beta (softmax)
__global__ void compute_beta(const float* __restrict__ wpart, float* __restrict__ beta) {
    __shared__ float s[256];
    int t = threadIdx.x;
    float m[N_PATHS];
    for (int p = 0; p < N_PATHS; ++p) {
        s[t] = wpart[p * 256 + t];
        __syncthreads();
        for (int off = 128; off > 0; off >>= 1) {
            if (t < off) s[t] += s[t + off];
            __syncthreads();
        }
        m[p] = s[0] / (float)N_NODES;
        __syncthreads();
    }
    if (t == 0) {
        float mx = fmaxf(m[0], fmaxf(m[1], m[2]));
        float e0 = expf(m[0] - mx), e1 = expf(m[1] - mx), e2 = expf(m[2] - mx);
        float inv = 1.f / (e0 + e1 + e2);
        beta[0] = e0 * inv; beta[1] = e1 * inv; beta[2] = e2 * inv;
    }
}

// ----------------------------------------------------------------- final mix
__global__ __launch_bounds__(256) void final_mix(
    const float* __restrict__ zbuf, const float* __restrict__ beta,
    float* __restrict__ out) {
    int n = blockIdx.x;
    int c = threadIdx.x;
    float b0 = beta[0], b1 = beta[1], b2 = beta[2];
    size_t stride = (size_t)N_NODES * NC;
    size_t idx = (size_t)n * NC + c;
    out[idx] = b0 * zbuf[idx] + b1 * zbuf[idx + stride]
             + b2 * zbuf[idx + 2 * stride];
}

extern "C" void kernel_launch(void* const* d_in, const int* in_sizes, int n_in,
                              void* d_out, int out_size, void* d_ws, size_t ws_size,
                              hipStream_t stream) {
    const float* feat  = (const float*)d_in[0];
    const int*   edges = (const int*)d_in[1];
    const float* Ws    = (const float*)d_in[2];
    const float* al    = (const float*)d_in[3];
    const float* ar    = (const float*)d_in[4];
    const float* bias  = (const float*)d_in[5];
    const float* W1    = (const float*)d_in[6];
    const float* b1    = (const float*)d_in[7];
    const float* w2    = (const float*)d_in[8];
    float* out = (float*)d_out;

    // ---- workspace layout (256B-aligned slabs), ~199 MB total
    size_t off = 0;
    auto alloc = [&](size_t bytes) { size_t o = off; off += (bytes + 255) & ~(size_t)255; return o; };
    size_t zbuf_o  = alloc((size_t)N_PATHS * N_NODES * NC * 4);  // 153.6 MB
    size_t hbuf_o  = alloc((size_t)N_NODES * NC * 2);            // 25.6 MB (per path, bf16)
    size_t num_o   = alloc((size_t)N_EDGES * NH * 4);            // 12.8 MB (per path)
    size_t el_o    = alloc((size_t)N_NODES * NH * 4);
    size_t er_o    = alloc((size_t)N_NODES * NH * 4);
    size_t rs_o    = alloc((size_t)N_NODES * NH * 4);
    size_t csr_o   = alloc((size_t)N_EDGES * 4);
    size_t offs_o  = alloc((size_t)N_NODES * 4);
    size_t ctot_o  = alloc(256 * 4);
    size_t cbase_o = alloc(256 * 4);
    size_t beta_o  = alloc(256);
    size_t deg_o    = alloc((size_t)N_NODES * 4);
    size_t cursor_o = alloc((size_t)N_NODES * 4);
    size_t zend_o   = off;
    size_t wpart_o  = alloc((size_t)N_PATHS * 256 * 4);
    size_t total = off;
    if (ws_size < total) return;  // fail loudly (zero output)

    char* ws = (char*)d_ws;
    float*          zbuf  = (float*)(ws + zbuf_o);
    unsigned short* hbuf  = (unsigned short*)(ws + hbuf_o);
    float* num   = (float*)(ws + num_o);
    float* el    = (float*)(ws + el_o);
    float* er    = (float*)(ws + er_o);
    float* rs    = (float*)(ws + rs_o);
    int*   csr   = (int*)(ws + csr_o);
    int*   offs  = (int*)(ws + offs_o);
    int*   ctot  = (int*)(ws + ctot_o);
    int*   cbase = (int*)(ws + cbase_o);
    float* beta  = (float*)(ws + beta_o);
    int*   deg   = (int*)(ws + deg_o);
    int*   cursor= (int*)(ws + cursor_o);
    float* wpart = (float*)(ws + wpart_o);

    const int NCH = (N_NODES + 255) / 256;   // 196 scan chunks

    hipMemsetAsync(ws + wpart_o, 0, (size_t)N_PATHS * 256 * 4, stream);

    for (int p = 0; p < N_PATHS; ++p) {
        const int* edges_p = edges + (size_t)p * 2 * N_EDGES;
        hipMemsetAsync(ws + deg_o, 0, zend_o - deg_o, stream);  // deg + cursor
        gemm_node<<<(N_NODES + 63) / 64, 256, 0, stream>>>(
            feat, Ws, al, ar, hbuf, el, er, p);
        count_deg<<<(N_EDGES + 255) / 256, 256, 0, stream>>>(edges_p, deg);
        scan_chunk<<<NCH, 256, 0, stream>>>(deg, offs, ctot);
        scan_tot<<<1, 256, 0, stream>>>(ctot, cbase, NCH);
        add_base<<<NCH, 256, 0, stream>>>(offs, cbase);
        fill_csr<<<(N_EDGES + 255) / 256, 256, 0, stream>>>(edges_p, offs, cursor, csr);
        phase_a<<<(N_NODES + 31) / 32, 256, 0, stream>>>(csr, offs, deg, el, er, num, rs);
        phase_b<<<N_NODES, 256, 0, stream>>>(csr, offs, deg, num, rs, hbuf, bias, zbuf, p);
    }
    semantic<<<dim3((N_NODES + 63) / 64, N_PATHS), 256, 0, stream>>>(
        zbuf, W1, b1, w2, wpart);
    compute_beta<<<1, 256, 0, stream>>>(wpart, beta);
    final_mix<<<N_NODES, 256, 0, stream>>>(zbuf, beta, out);
}

// Round 7
// 1037.435 us; speedup vs baseline: 2.9838x; 1.1629x over previous
//
#include <hip/hip_runtime.h>

// MPALayer (HAN-style): P=3 metapath GATs + semantic attention.
// Inputs/out FLOAT32; edges int32. Path-serial to fit ws (~199 MB).
// R6->R7: rotation-ordered W-tile reads in gemm_node (was 8-way LDS bank
// conflict: hd*32 ≡ 0 mod 32) and semantic (was 4-way: j0 on 2 bank groups,
// SQ_LDS_BANK_CONFLICT 3.85e7). Each read slot now spans 8 bank groups.

#define N_NODES 50000
#define N_EDGES 400000
#define N_PATHS 3
#define DIN     128
#define NH      8
#define NO      32
#define NC      256   // NH*NO
#define HID     128

__device__ __forceinline__ float bf2f(unsigned short u) {
    return __uint_as_float(((unsigned int)u) << 16);
}
__device__ __forceinline__ unsigned short f2bf(float f) {
    unsigned int u = __float_as_uint(f);
    unsigned int r = u + 0x7FFFu + ((u >> 16) & 1u);   // RNE
    return (unsigned short)(r >> 16);
}

// ------------------------------------------------- node GEMM h = feat @ W_p
// grid ceil(N/64), block 256. Thread = (node-pair g, head hd): 2 nodes x 32 ch.
// W chunk 32x256 in LDS; thread hd visits its 8 float4 chunks rotated by hd
// so each ds_read_b128 slot hits 8 distinct bank groups (conflict-free).
__global__ __launch_bounds__(256) void gemm_node(
    const float* __restrict__ feat, const float* __restrict__ Ws,
    const float* __restrict__ al, const float* __restrict__ ar,
    unsigned short* __restrict__ hbuf, float* __restrict__ el,
    float* __restrict__ er, int p) {
    int tile = blockIdx.x * 64;
    int t = threadIdx.x;
    int hd = t & 7;
    int g  = t >> 3;                    // 0..31 -> node pair
    int ln0 = g * 2, ln1 = ln0 + 1;

    __shared__ float fs[64][36];        // 64 nodes x 32 k (pad 32->36)
    __shared__ float wls[32 * 256];     // 32 KiB

    float acc0[32], acc1[32];
#pragma unroll
    for (int o = 0; o < 32; ++o) { acc0[o] = 0.f; acc1[o] = 0.f; }

    const float* wsrc_base = Ws + (size_t)p * DIN * NC;

    for (int k0 = 0; k0 < DIN; k0 += 32) {
        const float4* wsrc = (const float4*)(wsrc_base + (size_t)k0 * NC);
        float4* wdst = (float4*)wls;
#pragma unroll
        for (int i = 0; i < 8; ++i)
            wdst[i * 256 + t] = wsrc[i * 256 + t];
#pragma unroll
        for (int i = 0; i < 2; ++i) {
            int q = i * 256 + t;        // 0..511 float4 slots
            int node = q >> 3;
            int kq = (q & 7) * 4;
            int n = tile + node;
            float4 v = make_float4(0.f, 0.f, 0.f, 0.f);
            if (n < N_NODES)
                v = *(const float4*)(feat + (size_t)n * DIN + k0 + kq);
            fs[node][kq + 0] = v.x; fs[node][kq + 1] = v.y;
            fs[node][kq + 2] = v.z; fs[node][kq + 3] = v.w;
        }
        __syncthreads();

        for (int kk = 0; kk < 32; ++kk) {
            float a0 = fs[ln0][kk];
            float a1 = fs[ln1][kk];
            const float4* wr = (const float4*)(wls + kk * 256 + hd * 32);
#pragma unroll
            for (int qq = 0; qq < 8; ++qq) {
                int q = (qq + hd) & 7;          // rotated visit order
                float4 w = wr[q];
                acc0[qq*4+0] += a0 * w.x; acc0[qq*4+1] += a0 * w.y;
                acc0[qq*4+2] += a0 * w.z; acc0[qq*4+3] += a0 * w.w;
                acc1[qq*4+0] += a1 * w.x; acc1[qq*4+1] += a1 * w.y;
                acc1[qq*4+2] += a1 * w.z; acc1[qq*4+3] += a1 * w.w;
            }
        }
        __syncthreads();
    }

    // acc[qq*4+j] holds within-head channel o = ((qq+hd)&7)*4 + j
    const float* alp = al + (p * NH + hd) * NO;
    const float* arp = ar + (p * NH + hd) * NO;
    float el0 = 0.f, er0 = 0.f, el1 = 0.f, er1 = 0.f;
#pragma unroll
    for (int qq = 0; qq < 8; ++qq) {
        int q = (qq + hd) & 7;
#pragma unroll
        for (int j = 0; j < 4; ++j) {
            float a = alp[q*4+j], r = arp[q*4+j];
            el0 += acc0[qq*4+j] * a; er0 += acc0[qq*4+j] * r;
            el1 += acc1[qq*4+j] * a; er1 += acc1[qq*4+j] * r;
        }
    }
    int n0 = tile + ln0, n1 = tile + ln1;
    if (n0 < N_NODES) {
        unsigned short* hb = hbuf + (size_t)n0 * NC + hd * 32;
#pragma unroll
        for (int qq = 0; qq < 8; ++qq) {
            int q = (qq + hd) & 7;
            uint2 pk;
            pk.x = (unsigned int)f2bf(acc0[qq*4+0]) | ((unsigned int)f2bf(acc0[qq*4+1]) << 16);
            pk.y = (unsigned int)f2bf(acc0[qq*4+2]) | ((unsigned int)f2bf(acc0[qq*4+3]) << 16);
            *(uint2*)(hb + q*4) = pk;
        }
        el[(size_t)n0 * NH + hd] = el0;
        er[(size_t)n0 * NH + hd] = er0;
    }
    if (n1 < N_NODES) {
        unsigned short* hb = hbuf + (size_t)n1 * NC + hd * 32;
#pragma unroll
        for (int qq = 0; qq < 8; ++qq) {
            int q = (qq + hd) & 7;
            uint2 pk;
            pk.x = (unsigned int)f2bf(acc1[qq*4+0]) | ((unsigned int)f2bf(acc1[qq*4+1]) << 16);
            pk.y = (unsigned int)f2bf(acc1[qq*4+2]) | ((unsigned int)f2bf(acc1[qq*4+3]) << 16);
            *(uint2*)(hb + q*4) = pk;
        }
        el[(size_t)n1 * NH + hd] = el1;
        er[(size_t)n1 * NH + hd] = er1;
    }
}

// ------------------------------------------------------------- degree count
__global__ void count_deg(const int* __restrict__ edges_p, int* __restrict__ deg) {
    int e = blockIdx.x * 256 + threadIdx.x;
    if (e >= N_EDGES) return;
    int dst = edges_p[N_EDGES + e];
    atomicAdd(&deg[dst], 1);
}

// ------------------------------------------------------- 3-phase exclusive scan
__global__ void scan_chunk(const int* __restrict__ deg, int* __restrict__ offs,
                           int* __restrict__ ctot) {
    int i = blockIdx.x * 256 + threadIdx.x;
    __shared__ int s[256];
    int v = (i < N_NODES) ? deg[i] : 0;
    int orig = v;
    for (int off = 1; off < 256; off <<= 1) {
        s[threadIdx.x] = v; __syncthreads();
        int add = (threadIdx.x >= off) ? s[threadIdx.x - off] : 0;
        __syncthreads();
        v += add;
    }
    if (i < N_NODES) offs[i] = v - orig;
    if (threadIdx.x == 255) ctot[blockIdx.x] = v;
}

__global__ void scan_tot(const int* __restrict__ ctot, int* __restrict__ cbase, int nch) {
    int t = threadIdx.x;
    __shared__ int s[256];
    int v = (t < nch) ? ctot[t] : 0;
    int orig = v;
    for (int off = 1; off < 256; off <<= 1) {
        s[t] = v; __syncthreads();
        int add = (t >= off) ? s[t - off] : 0;
        __syncthreads();
        v += add;
    }
    cbase[t] = v - orig;
}

__global__ void add_base(int* __restrict__ offs, const int* __restrict__ cbase) {
    int i = blockIdx.x * 256 + threadIdx.x;
    if (i < N_NODES) offs[i] += cbase[blockIdx.x];
}

// ------------------------------------------------------------------ CSR fill
__global__ void fill_csr(const int* __restrict__ edges_p, const int* __restrict__ offs,
                         int* __restrict__ cursor, int* __restrict__ csr) {
    int e = blockIdx.x * 256 + threadIdx.x;
    if (e >= N_EDGES) return;
    int src = edges_p[e], dst = edges_p[N_EDGES + e];
    int pos = atomicAdd(&cursor[dst], 1);
    csr[offs[dst] + pos] = src;
}

// ------------------------- Phase A: per (dst,head) segment max + exp numerators
__global__ __launch_bounds__(256) void phase_a(
    const int* __restrict__ csr, const int* __restrict__ offs, const int* __restrict__ deg,
    const float* __restrict__ el, const float* __restrict__ er,
    float* __restrict__ num, float* __restrict__ rs) {
    int t = threadIdx.x;
    int dst = blockIdx.x * 32 + (t >> 3);
    int hd = t & 7;
    if (dst >= N_NODES) return;
    int off = offs[dst];
    int d   = deg[dst];
    float erv = er[(size_t)dst * NH + hd];
    const int* cp = csr + off;
    float m = -1e30f;
    for (int j = 0; j < d; ++j) {
        int src = cp[j];
        float x = el[src * NH + hd] + erv;
        x = (x >= 0.f) ? x : 0.2f * x;
        m = fmaxf(m, x);
    }
    float s = 0.f;
    float* np_ = num + (size_t)off * NH + hd;
    for (int j = 0; j < d; ++j) {
        int src = cp[j];
        float x = el[src * NH + hd] + erv;
        x = (x >= 0.f) ? x : 0.2f * x;
        float v = expf(x - m);
        np_[(size_t)j * NH] = v;
        s += v;
    }
    rs[(size_t)dst * NH + hd] = (d > 0) ? 1.0f / s : 0.f;
}

// -------------------- Phase B: block per dst, thread per channel; z = elu(..)
__global__ __launch_bounds__(256) void phase_b(
    const int* __restrict__ csr, const int* __restrict__ offs, const int* __restrict__ deg,
    const float* __restrict__ num, const float* __restrict__ rs,
    const unsigned short* __restrict__ hbuf, const float* __restrict__ bias,
    float* __restrict__ zbuf, int p) {
    int dst = blockIdx.x;
    int c = threadIdx.x;
    int hd = c >> 5;
    int off = offs[dst];
    int d   = deg[dst];
    float rsv = rs[(size_t)dst * NH + hd];
    const int*   cp  = csr + off;
    const float* np_ = num + (size_t)off * NH;
    float acc = 0.f;
    for (int j = 0; j < d; ++j) {
        int src = cp[j];
        float a = np_[(size_t)j * NH + hd] * rsv;
        acc += a * bf2f(hbuf[(size_t)src * NC + c]);
    }
    float zv = acc + bias[p * NC + c];
    zv = (zv > 0.f) ? zv : expm1f(zv);
    zbuf[((size_t)p * N_NODES + dst) * NC + c] = zv;
}

// -------------- semantic: LDS-tiled GEMM, 64 nodes/block, K-chunks of 64.
// W1 reads rotation-ordered: slot ii reads chunk (ii + (h>>1))&3 so each
// ds_read_b128 slot spans 8 distinct bank groups (was 4-way conflicted).
__global__ __launch_bounds__(256) void semantic(
    const float* __restrict__ zbuf, const float* __restrict__ W1,
    const float* __restrict__ b1, const float* __restrict__ w2,
    float* __restrict__ wpart) {
    int p = blockIdx.y;
    int n0 = blockIdx.x * 64;
    int t = threadIdx.x;
    int pair = t >> 3;          // 0..31 -> local nodes pair*2, pair*2+1
    int h = t & 7;
    int j0 = h * 16;            // 16 hidden units per thread
    int rot = h >> 1;           // 0..3

    __shared__ float zs[64][68];        // 17.0 KiB (pad 64->68)
    __shared__ float w1s[64 * 128];     // 32 KiB
    __shared__ float red[64][8];        // 2 KiB

    float acc0[16], acc1[16];
#pragma unroll
    for (int i = 0; i < 16; ++i) { acc0[i] = 0.f; acc1[i] = 0.f; }

    int ln0 = pair * 2, ln1 = ln0 + 1;

    for (int k0 = 0; k0 < NC; k0 += 64) {
        const float4* wsrc = (const float4*)(W1 + (size_t)k0 * HID);
        float4* wdst = (float4*)w1s;
#pragma unroll
        for (int i = 0; i < 8; ++i)
            wdst[i * 256 + t] = wsrc[i * 256 + t];
#pragma unroll
        for (int i = 0; i < 4; ++i) {
            int q = i * 256 + t;        // 0..1023 float4 slots
            int node = q >> 4;
            int kq = (q & 15) * 4;
            int n = n0 + node;
            float4 v = make_float4(0.f, 0.f, 0.f, 0.f);
            if (n < N_NODES)
                v = *(const float4*)(zbuf + ((size_t)p * N_NODES + n) * NC + k0 + kq);
            zs[node][kq + 0] = v.x; zs[node][kq + 1] = v.y;
            zs[node][kq + 2] = v.z; zs[node][kq + 3] = v.w;
        }
        __syncthreads();

        for (int kk = 0; kk < 64; ++kk) {
            float z0 = zs[ln0][kk];
            float z1 = zs[ln1][kk];
            const float4* wr = (const float4*)(w1s + kk * 128 + j0);
#pragma unroll
            for (int ii = 0; ii < 4; ++ii) {
                int i = (ii + rot) & 3;         // rotated visit order
                float4 w = wr[i];
                acc0[ii*4+0] += z0 * w.x; acc0[ii*4+1] += z0 * w.y;
                acc0[ii*4+2] += z0 * w.z; acc0[ii*4+3] += z0 * w.w;
                acc1[ii*4+0] += z1 * w.x; acc1[ii*4+1] += z1 * w.y;
                acc1[ii*4+2] += z1 * w.z; acc1[ii*4+3] += z1 * w.w;
            }
        }
        __syncthreads();
    }

    // acc[ii*4+c] holds hidden unit j = j0 + ((ii+rot)&3)*4 + c
    float s0 = 0.f, s1 = 0.f;
#pragma unroll
    for (int ii = 0; ii < 4; ++ii) {
        int i = (ii + rot) & 3;
#pragma unroll
        for (int c = 0; c < 4; ++c) {
            int j = j0 + i*4 + c;
            float b = b1[j], wv = w2[j];
            s0 += tanhf(acc0[ii*4+c] + b) * wv;
            s1 += tanhf(acc1[ii*4+c] + b) * wv;
        }
    }
    red[ln0][h] = s0;
    red[ln1][h] = s1;
    __syncthreads();
    if (t < 64) {
        float s = 0.f;
#pragma unroll
        for (int g2 = 0; g2 < 8; ++g2) s += red[t][g2];
        if (n0 + t >= N_NODES) s = 0.f;     // mask tail nodes
        for (int o = 32; o > 0; o >>= 1)
            s += __shfl_down(s, o, 64);
        if (t == 0) atomicAdd(&wpart[p * 256 + (blockIdx.x & 255)], s);
    }
}

// ------------------------------------------------------------- beta (softmax)
__global__ void compute_beta(const float* __restrict__ wpart, float* __restrict__ beta) {
    __shared__ float s[256];
    int t = threadIdx.x;
    float m[N_PATHS];
    for (int p = 0; p < N_PATHS; ++p) {
        s[t] = wpart[p * 256 + t];
        __syncthreads();
        for (int off = 128; off > 0; off >>= 1) {
            if (t < off) s[t] += s[t + off];
            __syncthreads();
        }
        m[p] = s[0] / (float)N_NODES;
        __syncthreads();
    }
    if (t == 0) {
        float mx = fmaxf(m[0], fmaxf(m[1], m[2]));
        float e0 = expf(m[0] - mx), e1 = expf(m[1] - mx), e2 = expf(m[2] - mx);
        float inv = 1.f / (e0 + e1 + e2);
        beta[0] = e0 * inv; beta[1] = e1 * inv; beta[2] = e2 * inv;
    }
}

// ----------------------------------------------------------------- final mix
__global__ __launch_bounds__(256) void final_mix(
    const float* __restrict__ zbuf, const float* __restrict__ beta,
    float* __restrict__ out) {
    int n = blockIdx.x;
    int c = threadIdx.x;
    float b0 = beta[0], b1 = beta[1], b2 = beta[2];
    size_t stride = (size_t)N_NODES * NC;
    size_t idx = (size_t)n * NC + c;
    out[idx] = b0 * zbuf[idx] + b1 * zbuf[idx + stride]
             + b2 * zbuf[idx + 2 * stride];
}

extern "C" void kernel_launch(void* const* d_in, const int* in_sizes, int n_in,
                              void* d_out, int out_size, void* d_ws, size_t ws_size,
                              hipStream_t stream) {
    const float* feat  = (const float*)d_in[0];
    const int*   edges = (const int*)d_in[1];
    const float* Ws    = (const float*)d_in[2];
    const float* al    = (const float*)d_in[3];
    const float* ar    = (const float*)d_in[4];
    const float* bias  = (const float*)d_in[5];
    const float* W1    = (const float*)d_in[6];
    const float* b1    = (const float*)d_in[7];
    const float* w2    = (const float*)d_in[8];
    float* out = (float*)d_out;

    // ---- workspace layout (256B-aligned slabs), ~199 MB total
    size_t off = 0;
    auto alloc = [&](size_t bytes) { size_t o = off; off += (bytes + 255) & ~(size_t)255; return o; };
    size_t zbuf_o  = alloc((size_t)N_PATHS * N_NODES * NC * 4);  // 153.6 MB
    size_t hbuf_o  = alloc((size_t)N_NODES * NC * 2);            // 25.6 MB (per path, bf16)
    size_t num_o   = alloc((size_t)N_EDGES * NH * 4);            // 12.8 MB (per path)
    size_t el_o    = alloc((size_t)N_NODES * NH * 4);
    size_t er_o    = alloc((size_t)N_NODES * NH * 4);
    size_t rs_o    = alloc((size_t)N_NODES * NH * 4);
    size_t csr_o   = alloc((size_t)N_EDGES * 4);
    size_t offs_o  = alloc((size_t)N_NODES * 4);
    size_t ctot_o  = alloc(256 * 4);
    size_t cbase_o = alloc(256 * 4);
    size_t beta_o  = alloc(256);
    size_t deg_o    = alloc((size_t)N_NODES * 4);
    size_t cursor_o = alloc((size_t)N_NODES * 4);
    size_t zend_o   = off;
    size_t wpart_o  = alloc((size_t)N_PATHS * 256 * 4);
    size_t total = off;
    if (ws_size < total) return;  // fail loudly (zero output)

    char* ws = (char*)d_ws;
    float*          zbuf  = (float*)(ws + zbuf_o);
    unsigned short* hbuf  = (unsigned short*)(ws + hbuf_o);
    float* num   = (float*)(ws + num_o);
    float* el    = (float*)(ws + el_o);
    float* er    = (float*)(ws + er_o);
    float* rs    = (float*)(ws + rs_o);
    int*   csr   = (int*)(ws + csr_o);
    int*   offs  = (int*)(ws + offs_o);
    int*   ctot  = (int*)(ws + ctot_o);
    int*   cbase = (int*)(ws + cbase_o);
    float* beta  = (float*)(ws + beta_o);
    int*   deg   = (int*)(ws + deg_o);
    int*   cursor= (int*)(ws + cursor_o);
    float* wpart = (float*)(ws + wpart_o);

    const int NCH = (N_NODES + 255) / 256;   // 196 scan chunks

    hipMemsetAsync(ws + wpart_o, 0, (size_t)N_PATHS * 256 * 4, stream);

    for (int p = 0; p < N_PATHS; ++p) {
        const int* edges_p = edges + (size_t)p * 2 * N_EDGES;
        hipMemsetAsync(ws + deg_o, 0, zend_o - deg_o, stream);  // deg + cursor
        gemm_node<<<(N_NODES + 63) / 64, 256, 0, stream>>>(
            feat, Ws, al, ar, hbuf, el, er, p);
        count_deg<<<(N_EDGES + 255) / 256, 256, 0, stream>>>(edges_p, deg);
        scan_chunk<<<NCH, 256, 0, stream>>>(deg, offs, ctot);
        scan_tot<<<1, 256, 0, stream>>>(ctot, cbase, NCH);
        add_base<<<NCH, 256, 0, stream>>>(offs, cbase);
        fill_csr<<<(N_EDGES + 255) / 256, 256, 0, stream>>>(edges_p, offs, cursor, csr);
        phase_a<<<(N_NODES + 31) / 32, 256, 0, stream>>>(csr, offs, deg, el, er, num, rs);
        phase_b<<<N_NODES, 256, 0, stream>>>(csr, offs, deg, num, rs, hbuf, bias, zbuf, p);
    }
    semantic<<<dim3((N_NODES + 63) / 64, N_PATHS), 256, 0, stream>>>(
        zbuf, W1, b1, w2, wpart);
    compute_beta<<<1, 256, 0, stream>>>(wpart, beta);
    final_mix<<<N_NODES, 256, 0, stream>>>(zbuf, beta, out);
}